// Round 11
// baseline (292.587 us; speedup 1.0000x reference)
//
#include <hip/hip_runtime.h>

typedef __bf16 bf16;
typedef __bf16 bf16x8 __attribute__((ext_vector_type(8)));
typedef float  f32x4  __attribute__((ext_vector_type(4)));
typedef float  f32x16 __attribute__((ext_vector_type(16)));
typedef unsigned int u32x4 __attribute__((ext_vector_type(4)));

#define KK     9
#define KDIM   2304
#define KSTEPS 144           // KDIM / 16  (K-steps of the 32x32x16 MFMA)
#define PXT    32            // pixels per tile (full-K LDS resident)

__device__ __forceinline__ int sreadi(int v) {
    return __builtin_amdgcn_readfirstlane(v);
}

// bf16 pair unpack (uint = 2 packed bf16)
__device__ __forceinline__ float BL(unsigned v) {
    return __builtin_bit_cast(float, v << 16);
}
__device__ __forceinline__ float BH(unsigned v) {
    return __builtin_bit_cast(float, v & 0xffff0000u);
}

// ---------------------------------------------------------------------------
// prep2_k: unchanged (verified rounds 4-10).
// ---------------------------------------------------------------------------
__global__ __launch_bounds__(256) void prep2_k(const float* __restrict__ x,
                                               const float* __restrict__ w,
                                               bf16* __restrict__ xt,
                                               bf16* __restrict__ wq) {
    __shared__ __align__(16) char smem[8 * 2308 * 2];   // 36928 B, aliased
    int bid = blockIdx.x;
    int tid = threadIdx.x;
    if (bid < 1024) {
        float (*tileF)[65] = reinterpret_cast<float(*)[65]>(smem); // 16640 B
        int pt = bid & 63, ct = (bid >> 6) & 3, b = bid >> 8;
        const float* src = x + ((size_t)(b * 256 + ct * 64)) * 4096 + pt * 64;
        int f4 = tid & 15;           // pixel quad
        int cl = tid >> 4;           // channel (base)
        #pragma unroll
        for (int q = 0; q < 4; ++q) {
            int c = q * 16 + cl;
            f32x4 v = *reinterpret_cast<const f32x4*>(src + (size_t)c * 4096 + f4 * 4);
            tileF[f4 * 4 + 0][c] = v[0];
            tileF[f4 * 4 + 1][c] = v[1];
            tileF[f4 * 4 + 2][c] = v[2];
            tileF[f4 * 4 + 3][c] = v[3];
        }
        __syncthreads();
        int j = tid & 7, p0 = tid >> 3;
        bf16* dst = xt + ((size_t)(b * 4096 + pt * 64)) * 256 + ct * 64 + j * 8;
        #pragma unroll
        for (int pp = 0; pp < 2; ++pp) {
            int p = p0 + pp * 32;
            bf16x8 sv;
            #pragma unroll
            for (int k = 0; k < 8; ++k) sv[k] = (bf16)tileF[p][j * 8 + k];
            *reinterpret_cast<bf16x8*>(dst + (size_t)p * 256) = sv;
        }
    } else {
        bf16 (*Wl)[2308] = reinterpret_cast<bf16(*)[2308]>(smem);  // 36928 B
        int wb     = bid - 1024;        // 0..31
        int o_base = wb * 8;
        int m      = o_base >> 5;
        int o31b   = o_base & 31;
        // stage 8 o-rows (coalesced float4) as bf16 in LDS
        #pragma unroll
        for (int pass = 0; pass < 18; ++pass) {
            int i    = pass * 256 + tid;        // < 4608 float4
            int r    = i / 576;
            int col4 = i - r * 576;
            f32x4 v = *reinterpret_cast<const f32x4*>(
                w + (size_t)(o_base + r) * KDIM + col4 * 4);
            Wl[r][col4 * 4 + 0] = (bf16)v[0];
            Wl[r][col4 * 4 + 1] = (bf16)v[1];
            Wl[r][col4 * 4 + 2] = (bf16)v[2];
            Wl[r][col4 * 4 + 3] = (bf16)v[3];
        }
        __syncthreads();
        // compose + store 2304 granules (9 per thread), coalesced in wq
        #pragma unroll
        for (int pass = 0; pass < 9; ++pass) {
            int gid  = pass * 256 + tid;        // < 2304
            int ol   = gid & 7;
            int half = (gid >> 3) & 1;
            int ks   = gid >> 4;                // 0..143
            int kb   = ks * 16 + half * 8;
            int tap  = kb >> 8;
            int cc0  = kb & 255;
            bf16x8 sv;
            #pragma unroll
            for (int j = 0; j < 8; ++j) sv[j] = Wl[ol][(cc0 + j) * 9 + tap];
            size_t g = (size_t)((m * KSTEPS + ks) * 64 + half * 32 + o31b + ol);
            *reinterpret_cast<bf16x8*>(wq + g * 8) = sv;
        }
    }
}

// ---------------------------------------------------------------------------
// deform_gemm_k v11: r10's phase-separated all-taps structure (correctness-
// verified) with BOUNDED instruction motion to kill r10's compiler-made
// spill (FETCH/WRITE 270/275 MB = scratch; 36 hoisted gathers = 144 VGPR):
//   phase S: 3 groups x 3 taps; sched_barrier(0) between groups caps live
//     gathers at 12 (~48 VGPR). No wave barriers inside (rows lane-private);
//     latency hidden by 4-way TLP + 3-body ILP.
//   phase G: tap loop ROLLED with explicit one-tap-ahead A prefetch
//     (af/an rotation, r6-proven): af 32 + an 32 + acc 16 ~= 90 VGPR < 128.
//   4 barriers/tile (vmcnt drains rare by design -- the r6/r9 per-tap
//   __syncthreads drained every prefetch; that lockstep is gone here).
// Grid 256 (1 WG/CU), 16 waves, 2 sequential 32-px tiles/WG, full-K
// S[9][32x256] = 147 KB. Granule-XOR swizzle (0 conflicts r1-r10),
// kh-epilogue via LDS, XCD banding (pblk high bits = bid&7), verbatim r10.
// ---------------------------------------------------------------------------
__global__ __launch_bounds__(1024, 4) void deform_gemm_k(
    const bf16*  __restrict__ xt,
    const float* __restrict__ off,
    const bf16*  __restrict__ wq,
    const float* __restrict__ bias,
    float*       __restrict__ out) {

    __shared__ bf16 S[KK][PXT * 256];   // 9 x 16 KB = 147,456 B

    int tid   = threadIdx.x;
    int wavei = sreadi(tid >> 6);   // 0..15
    int lane  = tid & 63;
    int l32   = lane & 31;
    int half  = lane >> 5;
    int mt    = wavei & 7;          // mtile (32 output channels)
    int kh    = wavei >> 3;         // K-half within each tap

    int bid = blockIdx.x;           // 0..255

    for (int tt = 0; tt < 2; ++tt) {
        int pblk  = ((bid & 7) << 6) | ((bid >> 3) << 1) | tt;  // 0..511
        int pix0  = pblk * PXT;
        int b     = pix0 >> 12;                  // tile-uniform batch
        int pimgb = pix0 & 4095;
        int obase = b * 73728;

        int n    = wavei * 2 + half;             // this lane's S row 0..31
        int pimg = pimgb + n;
        int py_i = pimg >> 6, px_i = pimg & 63;
        const char* xb = (const char*)xt + ((size_t)b << 21) + l32 * 16;

        // ===== phase S: sample all 9 taps, 3 groups of 3 (motion-fenced) ===
        #pragma unroll
        for (int tg = 0; tg < 3; ++tg) {
            #pragma unroll
            for (int ti = 0; ti < 3; ++ti) {
                int tap = tg * 3 + ti;
                int ty = tap / 3 - 1;
                int tx = tap % 3 - 1;
                float oy = off[obase + (2 * tap) * 4096 + pimg];
                float ox = off[obase + (2 * tap + 1) * 4096 + pimg];
                float py = (float)(py_i + ty) + oy;
                float px = (float)(px_i + tx) + ox;
                float fy = floorf(py), fx = floorf(px);
                int   y0 = (int)fy,    x0 = (int)fx;
                float wy1 = py - fy, wx1 = px - fx;
                float wy0 = 1.f - wy1, wx0 = 1.f - wx1;
                wy0 = ((unsigned)y0       < 64u) ? wy0 : 0.f;
                wy1 = ((unsigned)(y0 + 1) < 64u) ? wy1 : 0.f;
                wx0 = ((unsigned)x0       < 64u) ? wx0 : 0.f;
                wx1 = ((unsigned)(x0 + 1) < 64u) ? wx1 : 0.f;
                int yc0 = min(max(y0, 0), 63), yc1 = min(max(y0 + 1, 0), 63);
                int xc0 = min(max(x0, 0), 63), xc1 = min(max(x0 + 1, 0), 63);
                unsigned u0 = (unsigned)(yc0 * 64 + xc0) * 512u;
                unsigned u1 = (unsigned)(yc0 * 64 + xc1) * 512u;
                unsigned u2 = (unsigned)(yc1 * 64 + xc0) * 512u;
                unsigned u3 = (unsigned)(yc1 * 64 + xc1) * 512u;
                float w0 = wy0 * wx0, w1 = wy0 * wx1;
                float w2 = wy1 * wx0, w3 = wy1 * wx1;
                u32x4 g0 = *(const u32x4*)(xb + u0);
                u32x4 g1 = *(const u32x4*)(xb + u1);
                u32x4 g2 = *(const u32x4*)(xb + u2);
                u32x4 g3 = *(const u32x4*)(xb + u3);
                bf16x8 sv;
                #pragma unroll
                for (int q = 0; q < 4; ++q) {
                    float lo = fmaf(w0, BL(g0[q]), fmaf(w1, BL(g1[q]),
                               fmaf(w2, BL(g2[q]),      w3 * BL(g3[q]))));
                    float hi = fmaf(w0, BH(g0[q]), fmaf(w1, BH(g1[q]),
                               fmaf(w2, BH(g2[q]),      w3 * BH(g3[q]))));
                    sv[q * 2]     = (bf16)lo;
                    sv[q * 2 + 1] = (bf16)hi;
                }
                int gsw = l32 ^ n;                 // granule-XOR swizzle
                *reinterpret_cast<bf16x8*>(&S[tap][0] + n * 256 + gsw * 8) = sv;
            }
            // fence: cap live gathers at one group's worth (12 x u32x4)
            __builtin_amdgcn_sched_barrier(0);
        }

        __syncthreads();   // S complete

        // ===== phase G: streaming GEMM, rolled taps + 1-ahead A prefetch ===
        f32x16 acc;
        #pragma unroll
        for (int r = 0; r < 16; ++r) acc[r] = 0.f;

        bf16x8 af[8];
        {
            const bf16* ap0 = wq +
                ((size_t)(((mt * KSTEPS) + kh * 8) * 64 + lane)) * 8;
            #pragma unroll
            for (int s = 0; s < 8; ++s)
                af[s] = *reinterpret_cast<const bf16x8*>(ap0 + (size_t)s * 512);
        }
        for (int tap = 0; tap < KK; ++tap) {
            bf16x8 an[8];
            if (tap < KK - 1) {
                const bf16* apn = wq +
                    ((size_t)(((mt * KSTEPS) + (tap + 1) * 16 + kh * 8) * 64
                              + lane)) * 8;
                #pragma unroll
                for (int s = 0; s < 8; ++s)
                    an[s] = *reinterpret_cast<const bf16x8*>(apn + (size_t)s * 512);
            }
            const bf16* Sr = &S[tap][0];
            #pragma unroll
            for (int s = 0; s < 8; ++s) {
                int g  = (kh * 8 + s) * 2 + half;   // 16B granule
                int gs = g ^ l32;                   // row = l32
                bf16x8 bv = *reinterpret_cast<const bf16x8*>(Sr + l32 * 256 + gs * 8);
                acc = __builtin_amdgcn_mfma_f32_32x32x16_bf16(af[s], bv, acc, 0, 0, 0);
            }
            if (tap < KK - 1) {
                #pragma unroll
                for (int s = 0; s < 8; ++s) af[s] = an[s];
            }
        }

        __syncthreads();   // all S reads done; S reusable as Sf

        // ============ epilogue (verbatim r10): kh-reduce + store ==========
        float* Sf = reinterpret_cast<float*>(&S[0][0]);   // 8192 f32 = 32 KB
        if (kh == 1) {
            int wb = (wavei - 8) * 64 + lane;
            #pragma unroll
            for (int r = 0; r < 16; ++r)
                Sf[r * 512 + wb] = acc[r];   // lane-major: conflict-free b32
        }
        __syncthreads();
        if (kh == 0) {
            // C/D layout: col = lane&31, row = (r&3)+8*(r>>2)+4*half
            int wb   = wavei * 64 + lane;
            int m    = mt * 32;              // mt == wavei here (kh == 0)
            int pimo = pimgb + l32;
            float* op = out + ((size_t)(b * 256 + m)) * 4096 + pimo;
            #pragma unroll
            for (int r = 0; r < 16; ++r) {
                int row = (r & 3) + 8 * (r >> 2) + half * 4;
                float v = acc[r] + Sf[r * 512 + wb] + bias[m + row];
                op[(size_t)row * 4096] = v;
            }
        }
        __syncthreads();   // Sf reads done before next tile's sampling
    }
}

// ---------------------------------------------------------------------------
extern "C" void kernel_launch(void* const* d_in, const int* in_sizes, int n_in,
                              void* d_out, int out_size, void* d_ws, size_t ws_size,
                              hipStream_t stream) {
    const float* x    = (const float*)d_in[0];   // [4,256,64,64]
    const float* off  = (const float*)d_in[1];   // [4,18,64,64]
    const float* w    = (const float*)d_in[2];   // [256,256,3,3]
    const float* bias = (const float*)d_in[3];   // [256]
    float* out = (float*)d_out;                  // [4,256,64,64]

    bf16* wq = (bf16*)d_ws;                               // 1,179,648 B
    bf16* xt = (bf16*)((char*)d_ws + (size_t)589824 * 2); // 8,388,608 B

    prep2_k<<<1056, 256, 0, stream>>>(x, w, xt, wq);
    deform_gemm_k<<<256, 1024, 0, stream>>>(xt, off, wq, bias, out);
}

// Round 12
// 118.543 us; speedup vs baseline: 2.4682x; 2.4682x over previous
//
#include <hip/hip_runtime.h>

typedef __bf16 bf16;
typedef __bf16 bf16x8 __attribute__((ext_vector_type(8)));
typedef float  f32x4  __attribute__((ext_vector_type(4)));
typedef float  f32x16 __attribute__((ext_vector_type(16)));
typedef unsigned int u32x4 __attribute__((ext_vector_type(4)));

#define KK     9
#define KDIM   2304
#define KSTEPS 144           // KDIM / 16  (K-steps of the 32x32x16 MFMA)
#define PXT    32            // pixels per tile (full-K LDS resident)

__device__ __forceinline__ int sreadi(int v) {
    return __builtin_amdgcn_readfirstlane(v);
}

// bf16 pair unpack (uint = 2 packed bf16)
__device__ __forceinline__ float BL(unsigned v) {
    return __builtin_bit_cast(float, v << 16);
}
__device__ __forceinline__ float BH(unsigned v) {
    return __builtin_bit_cast(float, v & 0xffff0000u);
}

// ---------------------------------------------------------------------------
// prep2_k: unchanged (verified rounds 4-11).
// ---------------------------------------------------------------------------
__global__ __launch_bounds__(256) void prep2_k(const float* __restrict__ x,
                                               const float* __restrict__ w,
                                               bf16* __restrict__ xt,
                                               bf16* __restrict__ wq) {
    __shared__ __align__(16) char smem[8 * 2308 * 2];   // 36928 B, aliased
    int bid = blockIdx.x;
    int tid = threadIdx.x;
    if (bid < 1024) {
        float (*tileF)[65] = reinterpret_cast<float(*)[65]>(smem); // 16640 B
        int pt = bid & 63, ct = (bid >> 6) & 3, b = bid >> 8;
        const float* src = x + ((size_t)(b * 256 + ct * 64)) * 4096 + pt * 64;
        int f4 = tid & 15;           // pixel quad
        int cl = tid >> 4;           // channel (base)
        #pragma unroll
        for (int q = 0; q < 4; ++q) {
            int c = q * 16 + cl;
            f32x4 v = *reinterpret_cast<const f32x4*>(src + (size_t)c * 4096 + f4 * 4);
            tileF[f4 * 4 + 0][c] = v[0];
            tileF[f4 * 4 + 1][c] = v[1];
            tileF[f4 * 4 + 2][c] = v[2];
            tileF[f4 * 4 + 3][c] = v[3];
        }
        __syncthreads();
        int j = tid & 7, p0 = tid >> 3;
        bf16* dst = xt + ((size_t)(b * 4096 + pt * 64)) * 256 + ct * 64 + j * 8;
        #pragma unroll
        for (int pp = 0; pp < 2; ++pp) {
            int p = p0 + pp * 32;
            bf16x8 sv;
            #pragma unroll
            for (int k = 0; k < 8; ++k) sv[k] = (bf16)tileF[p][j * 8 + k];
            *reinterpret_cast<bf16x8*>(dst + (size_t)p * 256) = sv;
        }
    } else {
        bf16 (*Wl)[2308] = reinterpret_cast<bf16(*)[2308]>(smem);  // 36928 B
        int wb     = bid - 1024;        // 0..31
        int o_base = wb * 8;
        int m      = o_base >> 5;
        int o31b   = o_base & 31;
        // stage 8 o-rows (coalesced float4) as bf16 in LDS
        #pragma unroll
        for (int pass = 0; pass < 18; ++pass) {
            int i    = pass * 256 + tid;        // < 4608 float4
            int r    = i / 576;
            int col4 = i - r * 576;
            f32x4 v = *reinterpret_cast<const f32x4*>(
                w + (size_t)(o_base + r) * KDIM + col4 * 4);
            Wl[r][col4 * 4 + 0] = (bf16)v[0];
            Wl[r][col4 * 4 + 1] = (bf16)v[1];
            Wl[r][col4 * 4 + 2] = (bf16)v[2];
            Wl[r][col4 * 4 + 3] = (bf16)v[3];
        }
        __syncthreads();
        // compose + store 2304 granules (9 per thread), coalesced in wq
        #pragma unroll
        for (int pass = 0; pass < 9; ++pass) {
            int gid  = pass * 256 + tid;        // < 2304
            int ol   = gid & 7;
            int half = (gid >> 3) & 1;
            int ks   = gid >> 4;                // 0..143
            int kb   = ks * 16 + half * 8;
            int tap  = kb >> 8;
            int cc0  = kb & 255;
            bf16x8 sv;
            #pragma unroll
            for (int j = 0; j < 8; ++j) sv[j] = Wl[ol][(cc0 + j) * 9 + tap];
            size_t g = (size_t)((m * KSTEPS + ks) * 64 + half * 32 + o31b + ol);
            *reinterpret_cast<bf16x8*>(wq + g * 8) = sv;
        }
    }
}

// ---------------------------------------------------------------------------
// deform_gemm_k v12: r10's phase-separated all-taps structure (correctness-
// verified r10/r11) with HARD live-state minimization. Post-mortem of the
// two spills: the allocator's empirical budget here is 64 VGPR (VGPR_Count
// = 64 in r6/r10/r11 despite the (1024,4) hint); r10's spill = compiler
// fully unrolled phase S and hoisted 36 gathers (144 VGPR); r11's spill =
// my explicit af/an A-double-buffer (64 VGPR live across the rolled tap
// loop; WRITE 300 MB matches an[8] spill/fill arithmetic).
// Fix: #pragma unroll 1 on BOTH phase loops.
//   phase S (unroll 1): one tap's state live (~16 VGPR gathers, ~50 total);
//     no wave barriers inside; latency hidden by TLP (4 waves/SIMD).
//   phase G (unroll 1, direct-streamed A -- no prefetch arrays): 8
//     transient A-loads (32) + acc (16) ~= 55 VGPR; compiler's fine vmcnt
//     scheduling pipelines within each tap body (m97 lesson).
// 4 barriers/tile (8 total) vs r6/r9's 9 per-tap lockstep barriers.
// Grid 256 (1 WG/CU), 16 waves, 2 sequential 32-px tiles/WG, full-K
// S[9][32x256] = 147 KB. Granule-XOR swizzle (0 conflicts r1-r11),
// kh-epilogue via LDS, XCD banding, all verbatim r10.
// ---------------------------------------------------------------------------
__global__ __launch_bounds__(1024, 4) void deform_gemm_k(
    const bf16*  __restrict__ xt,
    const float* __restrict__ off,
    const bf16*  __restrict__ wq,
    const float* __restrict__ bias,
    float*       __restrict__ out) {

    __shared__ bf16 S[KK][PXT * 256];   // 9 x 16 KB = 147,456 B

    int tid   = threadIdx.x;
    int wavei = sreadi(tid >> 6);   // 0..15
    int lane  = tid & 63;
    int l32   = lane & 31;
    int half  = lane >> 5;
    int mt    = wavei & 7;          // mtile (32 output channels)
    int kh    = wavei >> 3;         // K-half within each tap

    int bid = blockIdx.x;           // 0..255

    for (int tt = 0; tt < 2; ++tt) {
        int pblk  = ((bid & 7) << 6) | ((bid >> 3) << 1) | tt;  // 0..511
        int pix0  = pblk * PXT;
        int b     = pix0 >> 12;                  // tile-uniform batch
        int pimgb = pix0 & 4095;
        int obase = b * 73728;

        int n    = wavei * 2 + half;             // this lane's S row 0..31
        int pimg = pimgb + n;
        int py_i = pimg >> 6, px_i = pimg & 63;
        const char* xb = (const char*)xt + ((size_t)b << 21) + l32 * 16;

        // ====== phase S: sample all 9 taps, loop NOT unrolled ======
        // (unroll 1 = the register-pressure fence: one tap's gathers live)
        #pragma unroll 1
        for (int tap = 0; tap < KK; ++tap) {
            int ty = tap / 3 - 1;
            int tx = tap % 3 - 1;
            float oy = off[obase + (2 * tap) * 4096 + pimg];
            float ox = off[obase + (2 * tap + 1) * 4096 + pimg];
            float py = (float)(py_i + ty) + oy;
            float px = (float)(px_i + tx) + ox;
            float fy = floorf(py), fx = floorf(px);
            int   y0 = (int)fy,    x0 = (int)fx;
            float wy1 = py - fy, wx1 = px - fx;
            float wy0 = 1.f - wy1, wx0 = 1.f - wx1;
            wy0 = ((unsigned)y0       < 64u) ? wy0 : 0.f;
            wy1 = ((unsigned)(y0 + 1) < 64u) ? wy1 : 0.f;
            wx0 = ((unsigned)x0       < 64u) ? wx0 : 0.f;
            wx1 = ((unsigned)(x0 + 1) < 64u) ? wx1 : 0.f;
            int yc0 = min(max(y0, 0), 63), yc1 = min(max(y0 + 1, 0), 63);
            int xc0 = min(max(x0, 0), 63), xc1 = min(max(x0 + 1, 0), 63);
            unsigned u0 = (unsigned)(yc0 * 64 + xc0) * 512u;
            unsigned u1 = (unsigned)(yc0 * 64 + xc1) * 512u;
            unsigned u2 = (unsigned)(yc1 * 64 + xc0) * 512u;
            unsigned u3 = (unsigned)(yc1 * 64 + xc1) * 512u;
            float w0 = wy0 * wx0, w1 = wy0 * wx1;
            float w2 = wy1 * wx0, w3 = wy1 * wx1;
            u32x4 g0 = *(const u32x4*)(xb + u0);
            u32x4 g1 = *(const u32x4*)(xb + u1);
            u32x4 g2 = *(const u32x4*)(xb + u2);
            u32x4 g3 = *(const u32x4*)(xb + u3);
            bf16x8 sv;
            #pragma unroll
            for (int q = 0; q < 4; ++q) {
                float lo = fmaf(w0, BL(g0[q]), fmaf(w1, BL(g1[q]),
                           fmaf(w2, BL(g2[q]),      w3 * BL(g3[q]))));
                float hi = fmaf(w0, BH(g0[q]), fmaf(w1, BH(g1[q]),
                           fmaf(w2, BH(g2[q]),      w3 * BH(g3[q]))));
                sv[q * 2]     = (bf16)lo;
                sv[q * 2 + 1] = (bf16)hi;
            }
            int gsw = l32 ^ n;                 // granule-XOR swizzle
            *reinterpret_cast<bf16x8*>(&S[tap][0] + n * 256 + gsw * 8) = sv;
        }

        __syncthreads();   // S complete

        // ====== phase G: streaming GEMM, loop NOT unrolled, direct A ======
        f32x16 acc;
        #pragma unroll
        for (int r = 0; r < 16; ++r) acc[r] = 0.f;

        #pragma unroll 1
        for (int tap = 0; tap < KK; ++tap) {
            const bf16* ap0 = wq +
                ((size_t)(((mt * KSTEPS) + tap * 16 + kh * 8) * 64 + lane)) * 8;
            const bf16* Sr = &S[tap][0];
            #pragma unroll
            for (int s = 0; s < 8; ++s) {
                bf16x8 a = *reinterpret_cast<const bf16x8*>(ap0 + (size_t)s * 512);
                int g  = (kh * 8 + s) * 2 + half;   // 16B granule
                int gs = g ^ l32;                   // row = l32
                bf16x8 bv = *reinterpret_cast<const bf16x8*>(Sr + l32 * 256 + gs * 8);
                acc = __builtin_amdgcn_mfma_f32_32x32x16_bf16(a, bv, acc, 0, 0, 0);
            }
        }

        __syncthreads();   // all S reads done; S reusable as Sf

        // ============ epilogue (verbatim r10): kh-reduce + store ==========
        float* Sf = reinterpret_cast<float*>(&S[0][0]);   // 8192 f32 = 32 KB
        if (kh == 1) {
            int wb = (wavei - 8) * 64 + lane;
            #pragma unroll
            for (int r = 0; r < 16; ++r)
                Sf[r * 512 + wb] = acc[r];   // lane-major: conflict-free b32
        }
        __syncthreads();
        if (kh == 0) {
            // C/D layout: col = lane&31, row = (r&3)+8*(r>>2)+4*half
            int wb   = wavei * 64 + lane;
            int m    = mt * 32;              // mt == wavei here (kh == 0)
            int pimo = pimgb + l32;
            float* op = out + ((size_t)(b * 256 + m)) * 4096 + pimo;
            #pragma unroll
            for (int r = 0; r < 16; ++r) {
                int row = (r & 3) + 8 * (r >> 2) + half * 4;
                float v = acc[r] + Sf[r * 512 + wb] + bias[m + row];
                op[(size_t)row * 4096] = v;
            }
        }
        __syncthreads();   // Sf reads done before next tile's sampling
    }
}

// ---------------------------------------------------------------------------
extern "C" void kernel_launch(void* const* d_in, const int* in_sizes, int n_in,
                              void* d_out, int out_size, void* d_ws, size_t ws_size,
                              hipStream_t stream) {
    const float* x    = (const float*)d_in[0];   // [4,256,64,64]
    const float* off  = (const float*)d_in[1];   // [4,18,64,64]
    const float* w    = (const float*)d_in[2];   // [256,256,3,3]
    const float* bias = (const float*)d_in[3];   // [256]
    float* out = (float*)d_out;                  // [4,256,64,64]

    bf16* wq = (bf16*)d_ws;                               // 1,179,648 B
    bf16* xt = (bf16*)((char*)d_ws + (size_t)589824 * 2); // 8,388,608 B

    prep2_k<<<1056, 256, 0, stream>>>(x, w, xt, wq);
    deform_gemm_k<<<256, 1024, 0, stream>>>(xt, off, wq, bias, out);
}